// Round 3
// baseline (5654.446 us; speedup 1.0000x reference)
//
#include <hip/hip_runtime.h>
#include <hip/hip_bf16.h>
#include <math.h>

#define D_MODEL 1024
#define N_HEADS 16
#define HEAD_DIM 64
#define D_FF 4096
#define N_LAYERS 4
#define VOCAB 2048
#define NUM_GROUPS 15
#define CACHE_LEN 17
#define EPS 1e-6f
#define NB 256   // blocks (1 per CU)
#define NT 1024  // threads per block (16 waves)

typedef unsigned short ushort8v __attribute__((ext_vector_type(8)));

__device__ __forceinline__ float bf2f(unsigned short u) {
  union { unsigned int i; float f; } c;
  c.i = ((unsigned int)u) << 16;
  return c.f;
}

__device__ __forceinline__ unsigned short f2bf(float f) {
  union { float f; unsigned int i; } c;
  c.f = f;
  unsigned int r = (c.i + 0x7fffu + ((c.i >> 16) & 1u)) >> 16;
  return (unsigned short)r;
}

__device__ __forceinline__ float wred(float v) {
#pragma unroll
  for (int o = 32; o > 0; o >>= 1) v += __shfl_xor(v, o, 64);
  return v;
}

__device__ __forceinline__ float wredmax(float v) {
#pragma unroll
  for (int o = 32; o > 0; o >>= 1) v = fmaxf(v, __shfl_xor(v, o, 64));
  return v;
}

struct Sh {
  float attn[2][D_MODEL];  // 16B-aligned at offset 0 (float4 LDS reads)
  float red[32];
  float scale[2];
  float bval[16];
  int bidx[16];
  int code;
};

// Monotonic grid barrier: each sync, every block adds 1; wait until cnt >= k*NB.
// Requires all blocks co-resident (cooperative launch). bar zeroed per call.
__device__ __forceinline__ void gsync(unsigned* bar, unsigned& tgt) {
  tgt += NB;
  __syncthreads();
  if (threadIdx.x == 0) {
    __threadfence();
    atomicAdd(bar, 1u);
    while (__hip_atomic_load(bar, __ATOMIC_RELAXED, __HIP_MEMORY_SCOPE_AGENT) < tgt)
      __builtin_amdgcn_s_sleep(1);
    __threadfence();
  }
  __syncthreads();
}

// rms scale of one 1024-row, all 1024 threads; result in sh.scale[s]
__device__ __forceinline__ void block_rms(const float* __restrict__ h, int s, Sh& sh) {
  int tid = threadIdx.x;
  float v = h[tid];
  float p = wred(v * v);
  if ((tid & 63) == 0) sh.red[tid >> 6] = p;
  __syncthreads();
  if (tid == 0) {
    float t = 0.f;
#pragma unroll
    for (int w = 0; w < 16; ++w) t += sh.red[w];
    sh.scale[s] = rsqrtf(t * (1.f / D_MODEL) + EPS);
  }
  __syncthreads();
}

// a[c] = x[off512*512 + lane*8 + c] * ln[...] * scale, c=0..7
__device__ __forceinline__ void load_act_off(const float* __restrict__ x,
                                             const float* __restrict__ ln,
                                             float scale, int off512, float* a) {
  int lane = threadIdx.x & 63;
  const float4* xv = (const float4*)(x + off512 * 512);
  const float4* lv = (const float4*)(ln + off512 * 512);
  float4 v0 = xv[lane * 2], v1 = xv[lane * 2 + 1];
  float4 l0 = lv[lane * 2], l1 = lv[lane * 2 + 1];
  a[0] = v0.x * l0.x * scale; a[1] = v0.y * l0.y * scale;
  a[2] = v0.z * l0.z * scale; a[3] = v0.w * l0.w * scale;
  a[4] = v1.x * l1.x * scale; a[5] = v1.y * l1.y * scale;
  a[6] = v1.z * l1.z * scale; a[7] = v1.w * l1.w * scale;
}

__device__ __forceinline__ void load_act(const float* __restrict__ x,
                                         const float* __restrict__ ln, float scale,
                                         float* a) {
  load_act_off(x, ln, scale, 0, a);
  load_act_off(x, ln, scale, 1, a + 8);
}

// dot: weight row vs register act a[NIT*8]; elements it*512+lane*8+c
template <typename WT, int NIT>
__device__ __forceinline__ float dot_cached(const WT* __restrict__ wrow, const float* a) {
  int lane = threadIdx.x & 63;
  float acc = 0.f;
  if constexpr (sizeof(WT) == 2) {
    const ushort8v* w8 = (const ushort8v*)wrow;
#pragma unroll
    for (int it = 0; it < NIT; ++it) {
      ushort8v w = w8[it * 64 + lane];
#pragma unroll
      for (int c = 0; c < 8; ++c) acc = fmaf(bf2f(w[c]), a[it * 8 + c], acc);
    }
  } else {
    const float4* w4 = (const float4*)wrow;
#pragma unroll
    for (int it = 0; it < NIT; ++it) {
      float4 b0 = w4[it * 128 + lane * 2];
      float4 b1 = w4[it * 128 + lane * 2 + 1];
      acc = fmaf(b0.x, a[it * 8 + 0], acc);
      acc = fmaf(b0.y, a[it * 8 + 1], acc);
      acc = fmaf(b0.z, a[it * 8 + 2], acc);
      acc = fmaf(b0.w, a[it * 8 + 3], acc);
      acc = fmaf(b1.x, a[it * 8 + 4], acc);
      acc = fmaf(b1.y, a[it * 8 + 5], acc);
      acc = fmaf(b1.z, a[it * 8 + 6], acc);
      acc = fmaf(b1.w, a[it * 8 + 7], acc);
    }
  }
  return wred(acc);
}

// dot: weight row vs act array in memory (global or LDS), same layout
template <typename WT, int NIT>
__device__ __forceinline__ float dot_stream(const WT* __restrict__ wrow,
                                            const float* __restrict__ act) {
  int lane = threadIdx.x & 63;
  const float4* av = (const float4*)act;
  float acc = 0.f;
  if constexpr (sizeof(WT) == 2) {
    const ushort8v* w8 = (const ushort8v*)wrow;
#pragma unroll
    for (int it = 0; it < NIT; ++it) {
      ushort8v w = w8[it * 64 + lane];
      float4 v0 = av[it * 128 + lane * 2];
      float4 v1 = av[it * 128 + lane * 2 + 1];
      acc = fmaf(bf2f(w[0]), v0.x, acc);
      acc = fmaf(bf2f(w[1]), v0.y, acc);
      acc = fmaf(bf2f(w[2]), v0.z, acc);
      acc = fmaf(bf2f(w[3]), v0.w, acc);
      acc = fmaf(bf2f(w[4]), v1.x, acc);
      acc = fmaf(bf2f(w[5]), v1.y, acc);
      acc = fmaf(bf2f(w[6]), v1.z, acc);
      acc = fmaf(bf2f(w[7]), v1.w, acc);
    }
  } else {
    const float4* w4 = (const float4*)wrow;
#pragma unroll
    for (int it = 0; it < NIT; ++it) {
      float4 b0 = w4[it * 128 + lane * 2];
      float4 b1 = w4[it * 128 + lane * 2 + 1];
      float4 v0 = av[it * 128 + lane * 2];
      float4 v1 = av[it * 128 + lane * 2 + 1];
      acc = fmaf(b0.x, v0.x, acc);
      acc = fmaf(b0.y, v0.y, acc);
      acc = fmaf(b0.z, v0.z, acc);
      acc = fmaf(b0.w, v0.w, acc);
      acc = fmaf(b1.x, v1.x, acc);
      acc = fmaf(b1.y, v1.y, acc);
      acc = fmaf(b1.z, v1.z, acc);
      acc = fmaf(b1.w, v1.w, acc);
    }
  }
  return wred(acc);
}

// first-index-tie-break argmax over lbuf[2048], all 1024 threads; broadcast code
__device__ __forceinline__ int block_argmax(const float* __restrict__ lbuf, Sh& sh) {
  int tid = threadIdx.x, lane = tid & 63, wv_ = tid >> 6;
  float v0 = lbuf[tid];
  int i0 = tid;
  float v1 = lbuf[tid + 1024];
  if (v1 > v0) { v0 = v1; i0 = tid + 1024; }
#pragma unroll
  for (int o = 32; o > 0; o >>= 1) {
    float v2 = __shfl_xor(v0, o, 64);
    int i2 = __shfl_xor(i0, o, 64);
    if (v2 > v0 || (v2 == v0 && i2 < i0)) { v0 = v2; i0 = i2; }
  }
  if (lane == 0) { sh.bval[wv_] = v0; sh.bidx[wv_] = i0; }
  __syncthreads();
  if (tid == 0) {
    float b = sh.bval[0];
    int bi = sh.bidx[0];
#pragma unroll
    for (int w = 1; w < 16; ++w) {
      float v = sh.bval[w];
      int i = sh.bidx[w];
      if (v > b || (v == b && i < bi)) { b = v; bi = i; }
    }
    sh.code = bi;
  }
  __syncthreads();
  return sh.code;
}

__device__ __forceinline__ void conv_arr(const float* __restrict__ src,
                                         unsigned short* __restrict__ dst, size_t n8) {
  const float4* s4 = (const float4*)src;
  ushort8v* d8 = (ushort8v*)dst;
  for (size_t i = (size_t)blockIdx.x * NT + threadIdx.x; i < n8; i += (size_t)NB * NT) {
    float4 a = s4[2 * i];
    float4 b = s4[2 * i + 1];
    ushort8v o;
    o[0] = f2bf(a.x); o[1] = f2bf(a.y); o[2] = f2bf(a.z); o[3] = f2bf(a.w);
    o[4] = f2bf(b.x); o[5] = f2bf(b.y); o[6] = f2bf(b.z); o[7] = f2bf(b.w);
    d8[i] = o;
  }
}

struct KParams {
  const float *th, *c0, *ln1, *ln2, *lnf, *heads, *embeds;
  const float *fwq, *fwk, *fwv, *fwo, *fw1, *fw2, *fw3;
  unsigned short *bwq, *bwk, *bwv, *bwo, *bw1, *bw2, *bw3;
  float *out, *x, *qb, *ff, *lbuf, *esum, *kc, *vc;
  unsigned* bar;
};

template <int BF> struct WSel;
template <> struct WSel<1> { using T = unsigned short; };
template <> struct WSel<0> { using T = float; };

__global__ void k_zero(unsigned* bar) {
  if (threadIdx.x == 0) *bar = 0;
}

template <int BF>
__global__ __launch_bounds__(NT, 4) void mega(KParams P) {
  using WT = typename WSel<BF>::T;
  __shared__ Sh sh;
  unsigned tgt = 0;
  const int tid = threadIdx.x, lane = tid & 63, wv_ = tid >> 6;

  const WT* wq = BF ? (const WT*)P.bwq : (const WT*)P.fwq;
  const WT* wk = BF ? (const WT*)P.bwk : (const WT*)P.fwk;
  const WT* wv = BF ? (const WT*)P.bwv : (const WT*)P.fwv;
  const WT* wo = BF ? (const WT*)P.bwo : (const WT*)P.fwo;
  const WT* w1 = BF ? (const WT*)P.bw1 : (const WT*)P.fw1;
  const WT* w2 = BF ? (const WT*)P.bw2 : (const WT*)P.fw2;
  const WT* w3 = BF ? (const WT*)P.bw3 : (const WT*)P.fw3;

  const size_t QKVO = (size_t)N_LAYERS * D_MODEL * D_MODEL;
  const size_t FFW = (size_t)N_LAYERS * D_FF * D_MODEL;

  // phase 0: weight convert (bf16 path) + setup
  if constexpr (BF) {
    conv_arr(P.fwq, P.bwq, QKVO / 8);
    conv_arr(P.fwk, P.bwk, QKVO / 8);
    conv_arr(P.fwv, P.bwv, QKVO / 8);
    conv_arr(P.fwo, P.bwo, QKVO / 8);
    conv_arr(P.fw1, P.bw1, FFW / 8);
    conv_arr(P.fw3, P.bw3, FFW / 8);
    conv_arr(P.fw2, P.bw2, FFW / 8);
  }
  if (blockIdx.x == 0) {
    P.x[tid] = P.th[tid];
    P.x[D_MODEL + tid] = P.c0[tid];
    P.esum[tid] = P.c0[tid];
  }
  gsync(P.bar, tgt);

  // ---- phase lambdas ----
  auto qkv_phase = [&](const float* hin, int S, int start, const float* ln,
                       const WT* Wq, const WT* Wk, const WT* Wv, float* kcl,
                       float* vcl) {
    for (int s = 0; s < S; ++s) block_rms(hin + s * D_MODEL, s, sh);
    if (wv_ < 6) {  // 6 busy waves per block -> 1536 tasks spread over all CUs
      int p = blockIdx.x * 6 + wv_;  // 0..1535
      int m = p / 512, pp = p & 511;
      const WT* W = (m == 0) ? Wq : (m == 1) ? Wk : Wv;
      const WT* r0 = W + (size_t)(2 * pp) * D_MODEL;
      const WT* r1 = r0 + D_MODEL;
      int h = (2 * pp) >> 6, dd = (2 * pp) & 63;
      for (int s = 0; s < S; ++s) {
        float a[16];
        load_act(hin + s * D_MODEL, ln, sh.scale[s], a);
        float d0 = dot_cached<WT, 2>(r0, a);
        float d1 = dot_cached<WT, 2>(r1, a);
        int pos = start + s;
        if (lane == 0) {
          if (m == 2) {
            vcl[(h * CACHE_LEN + pos) * HEAD_DIM + dd] = d0;
            vcl[(h * CACHE_LEN + pos) * HEAD_DIM + dd + 1] = d1;
          } else {
            int i = dd >> 1;
            float inv = powf(10000.f, -(float)(2 * i) / 64.f);
            float ang = (float)pos * inv;
            float c = cosf(ang), sn = sinf(ang);
            float o0 = d0 * c - d1 * sn;
            float o1 = d0 * sn + d1 * c;
            if (m == 0) {
              P.qb[s * D_MODEL + 2 * pp] = o0;
              P.qb[s * D_MODEL + 2 * pp + 1] = o1;
            } else {
              kcl[(h * CACHE_LEN + pos) * HEAD_DIM + dd] = o0;
              kcl[(h * CACHE_LEN + pos) * HEAD_DIM + dd + 1] = o1;
            }
          }
        }
      }
    }
  };

  auto aw_phase = [&](int S, int start, const WT* Wo, const float* kcl,
                      const float* vcl) {
    // redundant per-block attention: wave = head, lane-parallel softmax
    int h = wv_;
    for (int s = 0; s < S; ++s) {
      int pos = start + s;
      float qd = P.qb[s * D_MODEL + h * HEAD_DIM + lane];
      float sc = -1e30f;
      for (int t = 0; t <= pos; ++t) {
        float sum = wred(qd * kcl[(h * CACHE_LEN + t) * HEAD_DIM + lane]);
        if (lane == t) sc = sum * 0.125f;  // 1/sqrt(64)
      }
      float mx = wredmax(lane <= pos ? sc : -1e30f);
      float e = (lane <= pos) ? expf(sc - mx) : 0.f;
      float den = wred(e);
      float pr = e / den;
      float acc = 0.f;
      for (int t = 0; t <= pos; ++t)
        acc = fmaf(__shfl(pr, t, 64), vcl[(h * CACHE_LEN + t) * HEAD_DIM + lane], acc);
      sh.attn[s][h * HEAD_DIM + lane] = acc;
    }
    __syncthreads();
    // wo: 4 rows/block, 2 waves per row (512-elem halves)
    if (wv_ < 8) {
      int rr = wv_ >> 1, q = wv_ & 1;
      int row = blockIdx.x * 4 + rr;
      const WT* wrow = Wo + (size_t)row * D_MODEL;
      for (int s = 0; s < S; ++s) {
        float part = dot_stream<WT, 1>(wrow + q * 512, &sh.attn[s][q * 512]);
        if (lane == 0) sh.red[s * 16 + wv_] = part;
      }
    }
    __syncthreads();
    if (tid < 4 * S) {
      int s = tid >> 2, rr = tid & 3;
      P.x[s * D_MODEL + blockIdx.x * 4 + rr] +=
          sh.red[s * 16 + rr * 2] + sh.red[s * 16 + rr * 2 + 1];
    }
  };

  auto ffup_phase = [&](int S, const float* ln, const WT* W1, const WT* W3) {
    for (int s = 0; s < S; ++s) block_rms(P.x + s * D_MODEL, s, sh);
    int j = blockIdx.x * 16 + wv_;  // 0..4095, all waves busy
    const WT* r1 = W1 + (size_t)j * D_MODEL;
    const WT* r3 = W3 + (size_t)j * D_MODEL;
    for (int s = 0; s < S; ++s) {
      float a[16];
      load_act(P.x + s * D_MODEL, ln, sh.scale[s], a);
      float g = dot_cached<WT, 2>(r1, a);
      float u = dot_cached<WT, 2>(r3, a);
      if (lane == 0) P.ff[s * D_FF + j] = (g / (1.f + expf(-g))) * u;
    }
  };

  auto ffdown_phase = [&](int S, const WT* W2) {
    int rr = wv_ >> 2, q = wv_ & 3;
    int row = blockIdx.x * 4 + rr;
    const WT* wrow = W2 + (size_t)row * D_FF;
    for (int s = 0; s < S; ++s) {
      float pt = dot_stream<WT, 2>(wrow + q * 1024, P.ff + s * D_FF + q * 1024);
      if (lane == 0) sh.red[s * 16 + wv_] = pt;
    }
    __syncthreads();
    if (tid < 4 * S) {
      int s = tid >> 2, rr2 = tid & 3;
      float v = sh.red[s * 16 + rr2 * 4] + sh.red[s * 16 + rr2 * 4 + 1] +
                sh.red[s * 16 + rr2 * 4 + 2] + sh.red[s * 16 + rr2 * 4 + 3];
      P.x[s * D_MODEL + blockIdx.x * 4 + rr2] += v;
    }
  };

  auto logits_phase = [&](int row, const float* head, float* outg) {
    block_rms(P.x + row * D_MODEL, 0, sh);
    int j = blockIdx.x * 8 + (wv_ >> 1);  // 0..2047, all blocks busy
    int q = wv_ & 1;
    float a[8];
    load_act_off(P.x + row * D_MODEL, P.lnf, sh.scale[0], q, a);
    float part = dot_cached<float, 1>(head + (size_t)j * D_MODEL + q * 512, a);
    if (lane == 0) sh.red[wv_] = part;
    __syncthreads();
    if (tid < 8) {
      int j2 = blockIdx.x * 8 + tid;
      float d = sh.red[tid * 2] + sh.red[tid * 2 + 1];
      P.lbuf[j2] = d;
      outg[j2] = d;
    }
  };

  auto full_step = [&](int S, int start, bool am, const float* etab) {
    for (int l = 0; l < N_LAYERS; ++l) {
      const WT* Wq = wq + (size_t)l * D_MODEL * D_MODEL;
      const WT* Wk = wk + (size_t)l * D_MODEL * D_MODEL;
      const WT* Wv = wv + (size_t)l * D_MODEL * D_MODEL;
      const WT* Wo = wo + (size_t)l * D_MODEL * D_MODEL;
      const WT* W1 = w1 + (size_t)l * D_FF * D_MODEL;
      const WT* W2 = w2 + (size_t)l * D_FF * D_MODEL;
      const WT* W3 = w3 + (size_t)l * D_FF * D_MODEL;
      float* kcl = P.kc + (size_t)l * N_HEADS * CACHE_LEN * HEAD_DIM;
      float* vcl = P.vc + (size_t)l * N_HEADS * CACHE_LEN * HEAD_DIM;
      const float* hin = P.x;
      if (am && l == 0) {
        int code = block_argmax(P.lbuf, sh);
        hin = etab + (size_t)code * D_MODEL;
        if (blockIdx.x == 0) {
          float e = hin[tid];
          P.x[tid] = e;      // residual base for this step (row 0)
          P.esum[tid] += e;  // embed_sum accumulation
        }
      }
      qkv_phase(hin, S, start, P.ln1 + l * D_MODEL, Wq, Wk, Wv, kcl, vcl);
      gsync(P.bar, tgt);
      aw_phase(S, start, Wo, kcl, vcl);
      gsync(P.bar, tgt);
      ffup_phase(S, P.ln2 + l * D_MODEL, W1, W3);
      gsync(P.bar, tgt);
      ffdown_phase(S, W2);
      gsync(P.bar, tgt);
    }
  };

  // ---- flow ----
  full_step(2, 0, false, nullptr);  // prefill, positions {0,1}

  for (int g = 0; g < NUM_GROUPS; ++g) {
    logits_phase(g == 0 ? 1 : 0, P.heads + (size_t)g * VOCAB * D_MODEL,
                 P.out + (size_t)g * VOCAB);
    gsync(P.bar, tgt);
    if (g < NUM_GROUPS - 1) {
      full_step(1, 2 + g, true, P.embeds + (size_t)g * VOCAB * D_MODEL);
    } else {
      // tail: last argmax -> embed_sum output (transformer step after it is dead)
      if (blockIdx.x == 0) {
        int code = block_argmax(P.lbuf, sh);
        const float* emb =
            P.embeds + (size_t)g * VOCAB * D_MODEL + (size_t)code * D_MODEL;
        P.out[(size_t)NUM_GROUPS * VOCAB + tid] = P.esum[tid] + emb[tid];
      }
    }
  }
}

extern "C" void kernel_launch(void* const* d_in, const int* in_sizes, int n_in,
                              void* d_out, int out_size, void* d_ws, size_t ws_size,
                              hipStream_t stream) {
  KParams P;
  P.th = (const float*)d_in[0];
  P.c0 = (const float*)d_in[1];
  P.fwq = (const float*)d_in[2];
  P.fwk = (const float*)d_in[3];
  P.fwv = (const float*)d_in[4];
  P.fwo = (const float*)d_in[5];
  P.fw1 = (const float*)d_in[6];
  P.fw2 = (const float*)d_in[7];
  P.fw3 = (const float*)d_in[8];
  P.ln1 = (const float*)d_in[9];
  P.ln2 = (const float*)d_in[10];
  P.lnf = (const float*)d_in[11];
  P.heads = (const float*)d_in[12];
  P.embeds = (const float*)d_in[13];
  P.out = (float*)d_out;

  const size_t QKVO = (size_t)N_LAYERS * D_MODEL * D_MODEL;  // 4194304
  const size_t FFW = (size_t)N_LAYERS * D_FF * D_MODEL;      // 16777216
  const size_t W_ELEMS = 4 * QKVO + 3 * FFW;                 // 67108864
  // float scratch: x 2048 | qb 2048 | ff 8192 | lbuf 2048 | esum 1024 | kc 69632 | vc 69632
  const size_t SCRATCH = 2048 + 2048 + 8192 + 2048 + 1024 + 69632 + 69632;  // 154624
  const size_t NEED = W_ELEMS * 2 + SCRATCH * 4 + 256;

  float* fs;
  int use_bf16 = (ws_size >= NEED);
  if (use_bf16) {
    unsigned short* wb = (unsigned short*)d_ws;
    P.bwq = wb;
    P.bwk = wb + QKVO;
    P.bwv = wb + 2 * QKVO;
    P.bwo = wb + 3 * QKVO;
    P.bw1 = wb + 4 * QKVO;
    P.bw3 = wb + 4 * QKVO + FFW;
    P.bw2 = wb + 4 * QKVO + 2 * FFW;
    fs = (float*)(wb + W_ELEMS);
  } else {
    P.bwq = P.bwk = P.bwv = P.bwo = P.bw1 = P.bw2 = P.bw3 = nullptr;
    fs = (float*)d_ws;
  }
  P.x = fs;
  P.qb = fs + 2048;
  P.ff = fs + 4096;
  P.lbuf = fs + 12288;
  P.esum = fs + 14336;
  P.kc = fs + 15360;
  P.vc = fs + 84992;
  P.bar = (unsigned*)(fs + SCRATCH);

  k_zero<<<1, 64, 0, stream>>>(P.bar);
  void* args[] = {&P};
  if (use_bf16) {
    hipLaunchCooperativeKernel(reinterpret_cast<void*>(&mega<1>), dim3(NB), dim3(NT),
                               args, 0, stream);
  } else {
    hipLaunchCooperativeKernel(reinterpret_cast<void*>(&mega<0>), dim3(NB), dim3(NT),
                               args, 0, stream);
  }
}

// Round 4
// 1983.990 us; speedup vs baseline: 2.8500x; 2.8500x over previous
//
#include <hip/hip_runtime.h>
#include <math.h>

#define D_MODEL 1024
#define N_HEADS 16
#define HEAD_DIM 64
#define D_FF 4096
#define N_LAYERS 4
#define VOCAB 2048
#define NUM_GROUPS 15
#define CACHE_LEN 17
#define EPS 1e-6f
#define NB 256   // blocks (1 per CU)
#define NT 1024  // threads per block (16 waves)

typedef unsigned short ushort8v __attribute__((ext_vector_type(8)));

// ---------- coherent (device-scope, LLC-serialized) accessors ----------
// Cross-block data uses ONLY these: they compile to sc-flagged, L2-bypassing
// ops, so no threadfence (wbl2/inv) is ever needed; vmcnt drain at s_barrier
// (compiler-emitted before __syncthreads) makes them globally visible.
__device__ __forceinline__ float ldc(const float* p) {
  return __hip_atomic_load((float*)p, __ATOMIC_RELAXED, __HIP_MEMORY_SCOPE_AGENT);
}
__device__ __forceinline__ void stc(float* p, float v) {
  __hip_atomic_store(p, v, __ATOMIC_RELAXED, __HIP_MEMORY_SCOPE_AGENT);
}
__device__ __forceinline__ float2 ldc2(const float* p) {
  unsigned long long u = __hip_atomic_load((unsigned long long*)p, __ATOMIC_RELAXED,
                                           __HIP_MEMORY_SCOPE_AGENT);
  union { unsigned long long u; float2 f; } c;
  c.u = u;
  return c.f;
}
__device__ __forceinline__ void stc2(float* p, float a, float b) {
  union { unsigned long long u; float2 f; } c;
  c.f = make_float2(a, b);
  __hip_atomic_store((unsigned long long*)p, c.u, __ATOMIC_RELAXED,
                     __HIP_MEMORY_SCOPE_AGENT);
}
__device__ __forceinline__ void stc_u64(unsigned long long* p, unsigned long long v) {
  __hip_atomic_store(p, v, __ATOMIC_RELAXED, __HIP_MEMORY_SCOPE_AGENT);
}

__device__ __forceinline__ float bf2f(unsigned short u) {
  union { unsigned int i; float f; } c;
  c.i = ((unsigned int)u) << 16;
  return c.f;
}
__device__ __forceinline__ unsigned short f2bf(float f) {
  union { float f; unsigned int i; } c;
  c.f = f;
  unsigned int r = (c.i + 0x7fffu + ((c.i >> 16) & 1u)) >> 16;
  return (unsigned short)r;
}
__device__ __forceinline__ unsigned long long pack4bf(float4 v) {
  return (unsigned long long)f2bf(v.x) | ((unsigned long long)f2bf(v.y) << 16) |
         ((unsigned long long)f2bf(v.z) << 32) | ((unsigned long long)f2bf(v.w) << 48);
}

__device__ __forceinline__ float wred(float v) {
#pragma unroll
  for (int o = 32; o > 0; o >>= 1) v += __shfl_xor(v, o, 64);
  return v;
}

// ---------- hierarchical fence-free grid barrier ----------
// bar layout (uints): group g counter at [g*64] (g<8, 256B apart),
// master at [512], release flag at [576]. All zeroed per call by k_zero.
__device__ __forceinline__ void gsync(unsigned* bar, unsigned& gen) {
  __syncthreads();  // drains all waves' vmcnt -> sc-stores globally visible
  if (threadIdx.x == 0) {
    ++gen;
    unsigned* grp = bar + (blockIdx.x & 7) * 64;
    unsigned* master = bar + 512;
    unsigned* flag = bar + 576;
    bool released = false;
    unsigned old = __hip_atomic_fetch_add(grp, 1u, __ATOMIC_RELAXED,
                                          __HIP_MEMORY_SCOPE_AGENT);
    if (old == gen * (NB / 8) - 1) {  // last arriver of this group
      unsigned om = __hip_atomic_fetch_add(master, 1u, __ATOMIC_RELAXED,
                                           __HIP_MEMORY_SCOPE_AGENT);
      if (om == gen * 8 - 1) {  // last group closes the barrier
        __hip_atomic_store(flag, gen, __ATOMIC_RELAXED, __HIP_MEMORY_SCOPE_AGENT);
        released = true;
      }
    }
    if (!released) {
      while (__hip_atomic_load(flag, __ATOMIC_RELAXED, __HIP_MEMORY_SCOPE_AGENT) < gen)
        __builtin_amdgcn_s_sleep(4);
    }
  }
  __syncthreads();
}

// ---------- fused coherent-load + rmsnorm + ln scale ----------
// Each wave loads the FULL 1024-elem row (act layout: a[it*8+c] =
// x[it*512 + lane*8 + c]), computes sum(x^2) with one wave-reduce, scales.
__device__ __forceinline__ void load_act_rms(const float* __restrict__ x,
                                             const float* __restrict__ ln, float* a) {
  int lane = threadIdx.x & 63;
  float ssq = 0.f;
#pragma unroll
  for (int it = 0; it < 2; ++it) {
    const float* xp = x + it * 512 + lane * 8;
#pragma unroll
    for (int c = 0; c < 8; c += 2) {
      float2 v = ldc2(xp + c);
      a[it * 8 + c] = v.x;
      a[it * 8 + c + 1] = v.y;
      ssq = fmaf(v.x, v.x, fmaf(v.y, v.y, ssq));
    }
  }
  float scale = rsqrtf(wred(ssq) * (1.f / D_MODEL) + EPS);
  const float4* lv = (const float4*)ln;  // ln: immutable input, normal cached
#pragma unroll
  for (int it = 0; it < 2; ++it) {
    float4 l0 = lv[it * 128 + lane * 2];
    float4 l1 = lv[it * 128 + lane * 2 + 1];
    a[it * 8 + 0] *= l0.x * scale;
    a[it * 8 + 1] *= l0.y * scale;
    a[it * 8 + 2] *= l0.z * scale;
    a[it * 8 + 3] *= l0.w * scale;
    a[it * 8 + 4] *= l1.x * scale;
    a[it * 8 + 5] *= l1.y * scale;
    a[it * 8 + 6] *= l1.z * scale;
    a[it * 8 + 7] *= l1.w * scale;
  }
}

// dot: weight row (normal cached) vs register act a[NIT*8]
template <typename WT, int NIT>
__device__ __forceinline__ float dot_cached(const WT* __restrict__ wrow, const float* a) {
  int lane = threadIdx.x & 63;
  float acc = 0.f;
  if constexpr (sizeof(WT) == 2) {
    const ushort8v* w8 = (const ushort8v*)wrow;
#pragma unroll
    for (int it = 0; it < NIT; ++it) {
      ushort8v w = w8[it * 64 + lane];
#pragma unroll
      for (int c = 0; c < 8; ++c) acc = fmaf(bf2f(w[c]), a[it * 8 + c], acc);
    }
  } else {
    const float4* w4 = (const float4*)wrow;
#pragma unroll
    for (int it = 0; it < NIT; ++it) {
      float4 b0 = w4[it * 128 + lane * 2];
      float4 b1 = w4[it * 128 + lane * 2 + 1];
      acc = fmaf(b0.x, a[it * 8 + 0], acc);
      acc = fmaf(b0.y, a[it * 8 + 1], acc);
      acc = fmaf(b0.z, a[it * 8 + 2], acc);
      acc = fmaf(b0.w, a[it * 8 + 3], acc);
      acc = fmaf(b1.x, a[it * 8 + 4], acc);
      acc = fmaf(b1.y, a[it * 8 + 5], acc);
      acc = fmaf(b1.z, a[it * 8 + 6], acc);
      acc = fmaf(b1.w, a[it * 8 + 7], acc);
    }
  }
  return wred(acc);
}

// dot: weight row vs LDS act (normal loads both sides), n = NIT*512 elems
template <typename WT, int NIT>
__device__ __forceinline__ float dot_lds(const WT* __restrict__ wrow,
                                         const float* __restrict__ act) {
  int lane = threadIdx.x & 63;
  const float4* av = (const float4*)act;
  float acc = 0.f;
  if constexpr (sizeof(WT) == 2) {
    const ushort8v* w8 = (const ushort8v*)wrow;
#pragma unroll
    for (int it = 0; it < NIT; ++it) {
      ushort8v w = w8[it * 64 + lane];
      float4 v0 = av[it * 128 + lane * 2];
      float4 v1 = av[it * 128 + lane * 2 + 1];
      acc = fmaf(bf2f(w[0]), v0.x, acc);
      acc = fmaf(bf2f(w[1]), v0.y, acc);
      acc = fmaf(bf2f(w[2]), v0.z, acc);
      acc = fmaf(bf2f(w[3]), v0.w, acc);
      acc = fmaf(bf2f(w[4]), v1.x, acc);
      acc = fmaf(bf2f(w[5]), v1.y, acc);
      acc = fmaf(bf2f(w[6]), v1.z, acc);
      acc = fmaf(bf2f(w[7]), v1.w, acc);
    }
  } else {
    const float4* w4 = (const float4*)wrow;
#pragma unroll
    for (int it = 0; it < NIT; ++it) {
      float4 b0 = w4[it * 128 + lane * 2];
      float4 b1 = w4[it * 128 + lane * 2 + 1];
      float4 v0 = av[it * 128 + lane * 2];
      float4 v1 = av[it * 128 + lane * 2 + 1];
      acc = fmaf(b0.x, v0.x, acc);
      acc = fmaf(b0.y, v0.y, acc);
      acc = fmaf(b0.z, v0.z, acc);
      acc = fmaf(b0.w, v0.w, acc);
      acc = fmaf(b1.x, v1.x, acc);
      acc = fmaf(b1.y, v1.y, acc);
      acc = fmaf(b1.z, v1.z, acc);
      acc = fmaf(b1.w, v1.w, acc);
    }
  }
  return wred(acc);
}

// dot: weight quarter-row (1024 elems) vs coherent ff segment
template <typename WT>
__device__ __forceinline__ float dot_ffq(const WT* __restrict__ wrow,
                                         const float* __restrict__ ffq) {
  int lane = threadIdx.x & 63;
  float acc = 0.f;
#pragma unroll
  for (int it = 0; it < 2; ++it) {
    const float* fp = ffq + it * 512 + lane * 8;
    float2 v0 = ldc2(fp), v1 = ldc2(fp + 2), v2 = ldc2(fp + 4), v3 = ldc2(fp + 6);
    if constexpr (sizeof(WT) == 2) {
      ushort8v w = ((const ushort8v*)wrow)[it * 64 + lane];
      acc = fmaf(bf2f(w[0]), v0.x, acc);
      acc = fmaf(bf2f(w[1]), v0.y, acc);
      acc = fmaf(bf2f(w[2]), v1.x, acc);
      acc = fmaf(bf2f(w[3]), v1.y, acc);
      acc = fmaf(bf2f(w[4]), v2.x, acc);
      acc = fmaf(bf2f(w[5]), v2.y, acc);
      acc = fmaf(bf2f(w[6]), v3.x, acc);
      acc = fmaf(bf2f(w[7]), v3.y, acc);
    } else {
      const float4* w4 = (const float4*)wrow;
      float4 b0 = w4[it * 128 + lane * 2];
      float4 b1 = w4[it * 128 + lane * 2 + 1];
      acc = fmaf(b0.x, v0.x, acc);
      acc = fmaf(b0.y, v0.y, acc);
      acc = fmaf(b0.z, v1.x, acc);
      acc = fmaf(b0.w, v1.y, acc);
      acc = fmaf(b1.x, v2.x, acc);
      acc = fmaf(b1.y, v2.y, acc);
      acc = fmaf(b1.z, v3.x, acc);
      acc = fmaf(b1.w, v3.y, acc);
    }
  }
  return wred(acc);
}

struct Sh {
  float attn[2][D_MODEL];  // 8KB, float4-aligned
  float red[32];
  float bval[16];
  int bidx[16];
  int code;
};

// first-index-tie-break argmax over coherent lbuf[2048]
__device__ __forceinline__ int block_argmax(const float* __restrict__ lbuf, Sh& sh) {
  int tid = threadIdx.x, lane = tid & 63, wv_ = tid >> 6;
  float v0 = ldc(lbuf + tid);
  int i0 = tid;
  float v1 = ldc(lbuf + tid + 1024);
  if (v1 > v0) { v0 = v1; i0 = tid + 1024; }
#pragma unroll
  for (int o = 32; o > 0; o >>= 1) {
    float v2 = __shfl_xor(v0, o, 64);
    int i2 = __shfl_xor(i0, o, 64);
    if (v2 > v0 || (v2 == v0 && i2 < i0)) { v0 = v2; i0 = i2; }
  }
  if (lane == 0) { sh.bval[wv_] = v0; sh.bidx[wv_] = i0; }
  __syncthreads();
  if (tid == 0) {
    float b = sh.bval[0];
    int bi = sh.bidx[0];
#pragma unroll
    for (int w = 1; w < 16; ++w) {
      float v = sh.bval[w];
      int i = sh.bidx[w];
      if (v > b || (v == b && i < bi)) { b = v; bi = i; }
    }
    sh.code = bi;
  }
  __syncthreads();
  return sh.code;
}

__device__ __forceinline__ void conv_arr(const float* __restrict__ src,
                                         unsigned long long* __restrict__ dst,
                                         size_t n8) {
  const float4* s4 = (const float4*)src;
  for (size_t i = (size_t)blockIdx.x * NT + threadIdx.x; i < n8; i += (size_t)NB * NT) {
    float4 a = s4[2 * i];
    float4 b = s4[2 * i + 1];
    stc_u64(dst + 2 * i, pack4bf(a));
    stc_u64(dst + 2 * i + 1, pack4bf(b));
  }
}

struct KParams {
  const float *th, *c0, *ln1, *ln2, *lnf, *heads, *embeds;
  const float *fwq, *fwk, *fwv, *fwo, *fw1, *fw2, *fw3;
  unsigned short *bwq, *bwk, *bwv, *bwo, *bw1, *bw2, *bw3;
  float *out, *x, *qb, *ff, *lbuf, *esum, *kc, *vc;
  unsigned* bar;
};

template <int BF> struct WSel;
template <> struct WSel<1> { using T = unsigned short; };
template <> struct WSel<0> { using T = float; };

__global__ void k_zero(unsigned* bar) {
  if (threadIdx.x < 640) bar[threadIdx.x] = 0;
}

template <int BF>
__global__ __launch_bounds__(NT, 4) void mega(KParams P) {
  using WT = typename WSel<BF>::T;
  __shared__ Sh sh;
  unsigned gen = 0;
  const int tid = threadIdx.x, lane = tid & 63, wv_ = tid >> 6;

  const WT* wq = BF ? (const WT*)P.bwq : (const WT*)P.fwq;
  const WT* wk = BF ? (const WT*)P.bwk : (const WT*)P.fwk;
  const WT* wv = BF ? (const WT*)P.bwv : (const WT*)P.fwv;
  const WT* wo = BF ? (const WT*)P.bwo : (const WT*)P.fwo;
  const WT* w1 = BF ? (const WT*)P.bw1 : (const WT*)P.fw1;
  const WT* w2 = BF ? (const WT*)P.bw2 : (const WT*)P.fw2;
  const WT* w3 = BF ? (const WT*)P.bw3 : (const WT*)P.fw3;

  const size_t QKVO = (size_t)N_LAYERS * D_MODEL * D_MODEL;
  const size_t FFW = (size_t)N_LAYERS * D_FF * D_MODEL;

  // phase 0: weight convert (bf16 path) + setup
  if constexpr (BF) {
    conv_arr(P.fwq, (unsigned long long*)P.bwq, QKVO / 8);
    conv_arr(P.fwk, (unsigned long long*)P.bwk, QKVO / 8);
    conv_arr(P.fwv, (unsigned long long*)P.bwv, QKVO / 8);
    conv_arr(P.fwo, (unsigned long long*)P.bwo, QKVO / 8);
    conv_arr(P.fw1, (unsigned long long*)P.bw1, FFW / 8);
    conv_arr(P.fw3, (unsigned long long*)P.bw3, FFW / 8);
    conv_arr(P.fw2, (unsigned long long*)P.bw2, FFW / 8);
  }
  if (blockIdx.x == 0) {
    stc(&P.x[tid], P.th[tid]);
    stc(&P.x[D_MODEL + tid], P.c0[tid]);
    P.esum[tid] = P.c0[tid];  // block0-private across the whole call
  }
  gsync(P.bar, gen);

  // ---- phase lambdas ----
  // QKV: 12 busy waves/block, one 1024-row each (3072 rows total);
  // RoPE pairs (even,odd row) exchanged via LDS red[].
  auto qkv_phase = [&](const float* hin, int S, int start, const float* ln,
                       const WT* Wq, const WT* Wk, const WT* Wv, float* kcl,
                       float* vcl) {
    int R = blockIdx.x * 12 + wv_;  // 0..3071 for wv_<12
    int m = R >> 10, rr = R & 1023;
    int h = rr >> 6, dd = rr & 63;
    const WT* wrow = ((m == 0) ? Wq : (m == 1) ? Wk : Wv) + (size_t)rr * D_MODEL;
    for (int s = 0; s < S; ++s) {
      if (wv_ < 12) {
        float a[16];
        load_act_rms(hin + s * D_MODEL, ln, a);
        float d = dot_cached<WT, 2>(wrow, a);
        if (m == 2) {
          if (lane == 0) stc(&vcl[(h * CACHE_LEN + start + s) * HEAD_DIM + dd], d);
        } else {
          if (lane == 0) sh.red[s * 16 + wv_] = d;
        }
      }
    }
    __syncthreads();
    if (wv_ < 12 && m < 2 && !(rr & 1) && lane == 0) {
      int i = dd >> 1;
      float inv = powf(10000.f, -(float)(2 * i) / 64.f);
      for (int s = 0; s < S; ++s) {
        int pos = start + s;
        float d0 = sh.red[s * 16 + wv_];
        float d1 = sh.red[s * 16 + wv_ + 1];
        float ang = (float)pos * inv;
        float c = cosf(ang), sn = sinf(ang);
        float o0 = d0 * c - d1 * sn;
        float o1 = d0 * sn + d1 * c;
        if (m == 0) stc2(&P.qb[s * D_MODEL + rr], o0, o1);
        else stc2(&kcl[(h * CACHE_LEN + pos) * HEAD_DIM + dd], o0, o1);
      }
    }
  };

  // attention (redundant per block; wave=head) + Wo (4 rows/block) + residual
  auto aw_phase = [&](int S, int start, const WT* Wo, const float* kcl,
                      const float* vcl) {
    int h = wv_;
    for (int s = 0; s < S; ++s) {
      int pos = start + s;
      float qd = ldc(&P.qb[s * D_MODEL + h * HEAD_DIM + lane]);
      float sc = -1e30f;
      for (int t = 0; t <= pos; ++t) {
        float sum = wred(qd * ldc(&kcl[(h * CACHE_LEN + t) * HEAD_DIM + lane]));
        if (lane == t) sc = sum * 0.125f;  // 1/sqrt(64)
      }
      float mx = sc;
#pragma unroll
      for (int o = 32; o > 0; o >>= 1) mx = fmaxf(mx, __shfl_xor(mx, o, 64));
      float e = (lane <= pos) ? expf(sc - mx) : 0.f;
      float den = wred(e);
      float pr = e / den;
      float acc = 0.f;
      for (int t = 0; t <= pos; ++t)
        acc = fmaf(__shfl(pr, t, 64),
                   ldc(&vcl[(h * CACHE_LEN + t) * HEAD_DIM + lane]), acc);
      sh.attn[s][h * HEAD_DIM + lane] = acc;
    }
    __syncthreads();
    if (wv_ < 8) {  // 4 rows x 2 half-splits
      int rr = wv_ >> 1, q = wv_ & 1;
      int row = blockIdx.x * 4 + rr;
      const WT* wrow = Wo + (size_t)row * D_MODEL;
      for (int s = 0; s < S; ++s) {
        float part = dot_lds<WT, 1>(wrow + q * 512, &sh.attn[s][q * 512]);
        if (lane == 0) sh.red[s * 16 + wv_] = part;
      }
    }
    __syncthreads();
    if (tid < 4 * S) {
      int s = tid >> 2, rr = tid & 3;
      float* xp = &P.x[s * D_MODEL + blockIdx.x * 4 + rr];
      stc(xp, ldc(xp) + sh.red[s * 16 + rr * 2] + sh.red[s * 16 + rr * 2 + 1]);
    }
  };

  auto ffup_phase = [&](int S, const float* ln, const WT* W1, const WT* W3) {
    int j = blockIdx.x * 16 + wv_;  // 0..4095, all waves busy
    const WT* r1 = W1 + (size_t)j * D_MODEL;
    const WT* r3 = W3 + (size_t)j * D_MODEL;
    for (int s = 0; s < S; ++s) {
      float a[16];
      load_act_rms(P.x + s * D_MODEL, ln, a);
      float g = dot_cached<WT, 2>(r1, a);
      float u = dot_cached<WT, 2>(r3, a);
      if (lane == 0) stc(&P.ff[s * D_FF + j], (g / (1.f + expf(-g))) * u);
    }
  };

  auto ffdown_phase = [&](int S, const WT* W2) {
    int rr = wv_ >> 2, q = wv_ & 3;  // 4 rows x 4 quarter-splits
    int row = blockIdx.x * 4 + rr;
    const WT* wrow = W2 + (size_t)row * D_FF;
    for (int s = 0; s < S; ++s) {
      float pt = dot_ffq<WT>(wrow + q * 1024, P.ff + s * D_FF + q * 1024);
      if (lane == 0) sh.red[s * 16 + wv_] = pt;
    }
    __syncthreads();
    if (tid < 4 * S) {
      int s = tid >> 2, rr2 = tid & 3;
      float v = sh.red[s * 16 + rr2 * 4] + sh.red[s * 16 + rr2 * 4 + 1] +
                sh.red[s * 16 + rr2 * 4 + 2] + sh.red[s * 16 + rr2 * 4 + 3];
      float* xp = &P.x[s * D_MODEL + blockIdx.x * 4 + rr2];
      stc(xp, ldc(xp) + v);
    }
  };

  auto logits_phase = [&](int row, const float* head, float* outg) {
    if (wv_ < 8) {  // 8 rows/block, full-row dots
      int j = blockIdx.x * 8 + wv_;  // 0..2047
      float a[16];
      load_act_rms(P.x + row * D_MODEL, P.lnf, a);
      float d = dot_cached<float, 2>(head + (size_t)j * D_MODEL, a);
      if (lane == 0) {
        stc(&P.lbuf[j], d);
        outg[j] = d;
      }
    }
  };

  auto full_step = [&](int S, int start, bool am, const float* etab) {
    for (int l = 0; l < N_LAYERS; ++l) {
      const WT* Wq = wq + (size_t)l * D_MODEL * D_MODEL;
      const WT* Wk = wk + (size_t)l * D_MODEL * D_MODEL;
      const WT* Wv = wv + (size_t)l * D_MODEL * D_MODEL;
      const WT* Wo = wo + (size_t)l * D_MODEL * D_MODEL;
      const WT* W1 = w1 + (size_t)l * D_FF * D_MODEL;
      const WT* W2 = w2 + (size_t)l * D_FF * D_MODEL;
      const WT* W3 = w3 + (size_t)l * D_FF * D_MODEL;
      float* kcl = P.kc + (size_t)l * N_HEADS * CACHE_LEN * HEAD_DIM;
      float* vcl = P.vc + (size_t)l * N_HEADS * CACHE_LEN * HEAD_DIM;
      const float* hin = P.x;
      if (am && l == 0) {
        int code = block_argmax(P.lbuf, sh);
        hin = etab + (size_t)code * D_MODEL;  // immutable input row
        if (blockIdx.x == 0) {
          float e = hin[tid];
          stc(&P.x[tid], e);   // residual base (row 0), read by all after gsync
          P.esum[tid] += e;    // block0-private
        }
      }
      qkv_phase(hin, S, start, P.ln1 + l * D_MODEL, Wq, Wk, Wv, kcl, vcl);
      gsync(P.bar, gen);
      aw_phase(S, start, Wo, kcl, vcl);
      gsync(P.bar, gen);
      ffup_phase(S, P.ln2 + l * D_MODEL, W1, W3);
      gsync(P.bar, gen);
      ffdown_phase(S, W2);
      gsync(P.bar, gen);
    }
  };

  // ---- flow ----
  full_step(2, 0, false, nullptr);  // prefill, positions {0,1}

  for (int g = 0; g < NUM_GROUPS; ++g) {
    logits_phase(g == 0 ? 1 : 0, P.heads + (size_t)g * VOCAB * D_MODEL,
                 P.out + (size_t)g * VOCAB);
    gsync(P.bar, gen);
    if (g < NUM_GROUPS - 1) {
      full_step(1, 2 + g, true, P.embeds + (size_t)g * VOCAB * D_MODEL);
    } else {
      // tail: last argmax -> embed_sum output (the step after it is dead)
      if (blockIdx.x == 0) {
        int code = block_argmax(P.lbuf, sh);
        const float* emb =
            P.embeds + (size_t)g * VOCAB * D_MODEL + (size_t)code * D_MODEL;
        P.out[(size_t)NUM_GROUPS * VOCAB + tid] = P.esum[tid] + emb[tid];
      }
    }
  }
}

extern "C" void kernel_launch(void* const* d_in, const int* in_sizes, int n_in,
                              void* d_out, int out_size, void* d_ws, size_t ws_size,
                              hipStream_t stream) {
  KParams P;
  P.th = (const float*)d_in[0];
  P.c0 = (const float*)d_in[1];
  P.fwq = (const float*)d_in[2];
  P.fwk = (const float*)d_in[3];
  P.fwv = (const float*)d_in[4];
  P.fwo = (const float*)d_in[5];
  P.fw1 = (const float*)d_in[6];
  P.fw2 = (const float*)d_in[7];
  P.fw3 = (const float*)d_in[8];
  P.ln1 = (const float*)d_in[9];
  P.ln2 = (const float*)d_in[10];
  P.lnf = (const float*)d_in[11];
  P.heads = (const float*)d_in[12];
  P.embeds = (const float*)d_in[13];
  P.out = (float*)d_out;

  const size_t QKVO = (size_t)N_LAYERS * D_MODEL * D_MODEL;  // 4194304
  const size_t FFW = (size_t)N_LAYERS * D_FF * D_MODEL;      // 16777216
  const size_t W_ELEMS = 4 * QKVO + 3 * FFW;                 // 67108864
  // float scratch: x 2048 | qb 2048 | ff 8192 | lbuf 2048 | esum 1024 | kc 69632 | vc 69632
  const size_t SCRATCH = 2048 + 2048 + 8192 + 2048 + 1024 + 69632 + 69632;  // 154624
  const size_t NEED = W_ELEMS * 2 + (SCRATCH + 640) * 4;

  float* fs;
  int use_bf16 = (ws_size >= NEED);
  if (use_bf16) {
    unsigned short* wb = (unsigned short*)d_ws;
    P.bwq = wb;
    P.bwk = wb + QKVO;
    P.bwv = wb + 2 * QKVO;
    P.bwo = wb + 3 * QKVO;
    P.bw1 = wb + 4 * QKVO;
    P.bw3 = wb + 4 * QKVO + FFW;
    P.bw2 = wb + 4 * QKVO + 2 * FFW;
    fs = (float*)(wb + W_ELEMS);
  } else {
    P.bwq = P.bwk = P.bwv = P.bwo = P.bw1 = P.bw2 = P.bw3 = nullptr;
    fs = (float*)d_ws;
  }
  P.x = fs;
  P.qb = fs + 2048;
  P.ff = fs + 4096;
  P.lbuf = fs + 12288;
  P.esum = fs + 14336;
  P.kc = fs + 15360;
  P.vc = fs + 84992;
  P.bar = (unsigned*)(fs + SCRATCH);

  k_zero<<<1, 1024, 0, stream>>>(P.bar);
  void* args[] = {&P};
  if (use_bf16) {
    hipLaunchCooperativeKernel(reinterpret_cast<void*>(&mega<1>), dim3(NB), dim3(NT),
                               args, 0, stream);
  } else {
    hipLaunchCooperativeKernel(reinterpret_cast<void*>(&mega<0>), dim3(NB), dim3(NT),
                               args, 0, stream);
  }
}